// Round 2
// baseline (624.719 us; speedup 1.0000x reference)
//
#include <hip/hip_runtime.h>

// Problem constants
static constexpr int NN   = 50000;
static constexpr int EE   = 800000;
static constexpr int GG   = 256;

// ---------- helpers ----------
__device__ __forceinline__ int lowerb(const int* __restrict__ b, int n, int v) {
    int lo = 0, hi = n;
    while (lo < hi) { int m = (lo + hi) >> 1; if (b[m] < v) lo = m + 1; else hi = m; }
    return lo;
}

// ---------- CSR build (by target node = col) ----------
__global__ void count_k(const int* __restrict__ ei, int* __restrict__ cnt)
{
    int e = blockIdx.x * 256 + threadIdx.x;
    if (e < EE) atomicAdd(&cnt[ei[EE + e]], 1);
}

__global__ __launch_bounds__(1024) void scan_k(const int* __restrict__ cnt,
                                               int* __restrict__ rowptr,
                                               int* __restrict__ cursor,
                                               float* __restrict__ dinv)
{
    __shared__ int sums[1024];
    const int CH = (NN + 1023) / 1024;   // 49
    int t = threadIdx.x;
    int start = t * CH, end = min(start + CH, NN);
    int s = 0;
    for (int i = start; i < end; i++) s += cnt[i];
    sums[t] = s;
    __syncthreads();
    for (int off = 1; off < 1024; off <<= 1) {
        int v = sums[t];
        int add = (t >= off) ? sums[t - off] : 0;
        __syncthreads();
        sums[t] = v + add;
        __syncthreads();
    }
    int run = (t == 0) ? 0 : sums[t - 1];
    for (int i = start; i < end; i++) {
        rowptr[i] = run;
        cursor[i] = run;
        dinv[i]   = rsqrtf((float)(cnt[i] + 1));   // deg includes self-loop
        run += cnt[i];
    }
    if (t == 1023) rowptr[NN] = sums[1023];
}

__global__ void fill_k(const int* __restrict__ ei, const float* __restrict__ dinv,
                       int* __restrict__ cursor, int* __restrict__ csr_src,
                       float* __restrict__ csr_norm)
{
    int e = blockIdx.x * 256 + threadIdx.x;
    if (e < EE) {
        int r = ei[e];          // source
        int c = ei[EE + e];     // target
        int p = atomicAdd(&cursor[c], 1);
        csr_src[p]  = r;
        csr_norm[p] = dinv[r] * dinv[c];
    }
}

// ---------- GEMM: out[r][c0..c0+32) = in[r][:] @ W[:, c0..c0+32)   (W row-major [128][128]) ----------
// thread = 1 row; blockIdx.y = column quarter. Weight loads are wave-uniform -> scalar (s_load) path.
__global__ __launch_bounds__(256) void gemm128f_k(const float* __restrict__ in,
                                                  const float* __restrict__ W,
                                                  float* __restrict__ out,
                                                  int rows)
{
    int r = blockIdx.x * 256 + threadIdx.x;
    if (r >= rows) return;
    int c0 = blockIdx.y * 32;
    const float* rowp = in + (size_t)r * 128;

    float acc[32];
    #pragma unroll
    for (int j = 0; j < 32; j++) acc[j] = 0.f;

    for (int k0 = 0; k0 < 128; k0 += 8) {     // rolled: keeps code size sane
        float4 ra = *(const float4*)(rowp + k0);
        float4 rb = *(const float4*)(rowp + k0 + 4);
        float rr[8] = {ra.x, ra.y, ra.z, ra.w, rb.x, rb.y, rb.z, rb.w};
        #pragma unroll
        for (int kk = 0; kk < 8; kk++) {
            const float* wr = W + (size_t)(k0 + kk) * 128 + c0;   // wave-uniform
            #pragma unroll
            for (int j = 0; j < 32; j++) acc[j] = fmaf(rr[kk], wr[j], acc[j]);
        }
    }
    float* op = out + (size_t)r * 128 + c0;
    #pragma unroll
    for (int j = 0; j < 32; j += 4)
        *(float4*)(op + j) = make_float4(acc[j], acc[j+1], acc[j+2], acc[j+3]);
}

// ---------- aggregation: out[i] = relu?( sum_e norm*t[src] + dinv[i]^2 * t[i] + b ) ----------
// block = node, 64 threads, thread = float2 feature pair
__global__ __launch_bounds__(64) void aggf_k(const float* __restrict__ t,
                                             const int* __restrict__ rowptr,
                                             const int* __restrict__ csr_src,
                                             const float* __restrict__ csr_norm,
                                             const float* __restrict__ dinv,
                                             const float* __restrict__ bias,
                                             float* __restrict__ out,
                                             int relu)
{
    int i = blockIdx.x;
    int f = threadIdx.x;                      // float2 index, 64 covers 128 feats
    const float2* tp = (const float2*)t;
    float di = dinv[i];
    float sn = di * di;
    float2 v = tp[(size_t)i * 64 + f];
    float a0 = sn * v.x, a1 = sn * v.y;
    int e0 = rowptr[i], e1 = rowptr[i + 1];
    int e = e0;
    for (; e + 1 < e1; e += 2) {
        int s0 = csr_src[e],   s1 = csr_src[e + 1];
        float n0 = csr_norm[e], n1 = csr_norm[e + 1];
        float2 w0 = tp[(size_t)s0 * 64 + f];
        float2 w1 = tp[(size_t)s1 * 64 + f];
        a0 += n0 * w0.x; a1 += n0 * w0.y;
        a0 += n1 * w1.x; a1 += n1 * w1.y;
    }
    if (e < e1) {
        int s = csr_src[e];
        float nm = csr_norm[e];
        float2 w = tp[(size_t)s * 64 + f];
        a0 += nm * w.x; a1 += nm * w.y;
    }
    float2 b = ((const float2*)bias)[f];
    a0 += b.x; a1 += b.y;
    if (relu) { a0 = fmaxf(a0, 0.f); a1 = fmaxf(a1, 0.f); }
    ((float2*)out)[(size_t)i * 64 + f] = make_float2(a0, a1);
}

// conv3 aggregation: t row for node j is zz[batch[j]] (zz = z@W3, [G][128]); no relu
__global__ __launch_bounds__(64) void agg_out_k(const float* __restrict__ zz,
                                                const int* __restrict__ batch,
                                                const int* __restrict__ rowptr,
                                                const int* __restrict__ csr_src,
                                                const float* __restrict__ csr_norm,
                                                const float* __restrict__ dinv,
                                                const float* __restrict__ bias,
                                                float* __restrict__ out)
{
    int i = blockIdx.x;
    int f = threadIdx.x;
    const float2* zp = (const float2*)zz;     // only G*128 floats: L2-resident
    float di = dinv[i];
    float sn = di * di;
    float2 v = zp[(size_t)batch[i] * 64 + f];
    float a0 = sn * v.x, a1 = sn * v.y;
    int e0 = rowptr[i], e1 = rowptr[i + 1];
    for (int e = e0; e < e1; e++) {
        int s = csr_src[e];
        float nm = csr_norm[e];
        float2 w = zp[(size_t)batch[s] * 64 + f];
        a0 += nm * w.x; a1 += nm * w.y;
    }
    float2 b = ((const float2*)bias)[f];
    a0 += b.x; a1 += b.y;
    ((float2*)out)[(size_t)i * 64 + f] = make_float2(a0, a1);
}

// ---------- pooling: pooled[g][f] = sum over batch segment ----------
__global__ __launch_bounds__(128) void pool_k(const float* __restrict__ h2,
                                              const int* __restrict__ batch,
                                              float* __restrict__ pooled)
{
    int g = blockIdx.x;
    int f = threadIdx.x;                       // 0..127
    int bs = lowerb(batch, NN, g);
    int be = lowerb(batch, NN, g + 1);
    float a = 0.f;
    for (int i = bs; i < be; i++) a += h2[(size_t)i * 128 + f];
    pooled[(size_t)g * 128 + f] = a;
}

// ---------- fc: latent = relu(pooled @ fcW + fcb); writes latent to d_out too ----------
__global__ __launch_bounds__(64) void fc_k(const float* __restrict__ pooled,
                                           const float* __restrict__ fcW,    // [128][64]
                                           const float* __restrict__ fcb,
                                           float* __restrict__ latentf,
                                           float* __restrict__ lat_out)
{
    int g = blockIdx.x, l = threadIdx.x;       // 64 threads
    const float* p = pooled + (size_t)g * 128; // uniform scalar loads
    float a = fcb[l];
    #pragma unroll 8
    for (int k = 0; k < 128; k++) a = fmaf(p[k], fcW[(size_t)k * 64 + l], a);
    a = fmaxf(a, 0.f);
    latentf[(size_t)g * 64 + l] = a;
    lat_out[(size_t)g * 64 + l] = a;
}

// ---------- decoder + W3 transform: zz = relu(latent@decW + decb) @ W3 ----------
__global__ __launch_bounds__(128) void dec_k(const float* __restrict__ latentf,
                                             const float* __restrict__ decW,  // [64][128]
                                             const float* __restrict__ decb,
                                             const float* __restrict__ W3,    // [128][128]
                                             float* __restrict__ zz)
{
    __shared__ float zs[128];
    int g = blockIdx.x, c = threadIdx.x;       // 128 threads
    const float* lat = latentf + (size_t)g * 64;   // uniform
    {
        float a = decb[c];
        #pragma unroll 8
        for (int k = 0; k < 64; k++) a = fmaf(lat[k], decW[(size_t)k * 128 + c], a);
        zs[c] = fmaxf(a, 0.f);
    }
    __syncthreads();
    float o = 0.f;
    #pragma unroll 8
    for (int k = 0; k < 128; k++) o = fmaf(zs[k], W3[(size_t)k * 128 + c], o);
    zz[(size_t)g * 128 + c] = o;
}

extern "C" void kernel_launch(void* const* d_in, const int* in_sizes, int n_in,
                              void* d_out, int out_size, void* d_ws, size_t ws_size,
                              hipStream_t stream)
{
    const float* x     = (const float*)d_in[0];
    const int*   ei    = (const int*)d_in[1];
    const int*   batch = (const int*)d_in[2];
    const float* W1  = (const float*)d_in[3];
    const float* b1  = (const float*)d_in[4];
    const float* W2  = (const float*)d_in[5];
    const float* b2  = (const float*)d_in[6];
    const float* fcW = (const float*)d_in[7];
    const float* fcb = (const float*)d_in[8];
    const float* decW= (const float*)d_in[9];
    const float* decb= (const float*)d_in[10];
    const float* W3  = (const float*)d_in[11];
    const float* b3  = (const float*)d_in[12];

    char* ws = (char*)d_ws;
    size_t off = 0;
    auto alloc = [&](size_t bytes) -> char* {
        char* p = ws + off;
        off = (off + bytes + 255) & ~(size_t)255;
        return p;
    };
    float* dinv     = (float*)alloc((size_t)NN * 4);
    int*   cnt      = (int*)alloc((size_t)NN * 4);
    int*   rowptr   = (int*)alloc((size_t)(NN + 1) * 4);
    int*   cursor   = (int*)alloc((size_t)NN * 4);
    int*   csr_src  = (int*)alloc((size_t)EE * 4);
    float* csr_norm = (float*)alloc((size_t)EE * 4);
    float* pooled   = (float*)alloc((size_t)GG * 128 * 4);
    float* latentf  = (float*)alloc((size_t)GG * 64 * 4);
    float* zz       = (float*)alloc((size_t)GG * 128 * 4);
    float* A        = (float*)alloc((size_t)NN * 128 * 4);   // transformed features t
    float* B        = (float*)alloc((size_t)NN * 128 * 4);   // hidden activations h

    float* recon_out = (float*)d_out;
    float* lat_out   = (float*)d_out + (size_t)NN * 128;

    hipMemsetAsync(cnt, 0, (size_t)NN * 4, stream);
    count_k<<<(EE + 255) / 256, 256, 0, stream>>>(ei, cnt);
    scan_k<<<1, 1024, 0, stream>>>(cnt, rowptr, cursor, dinv);
    fill_k<<<(EE + 255) / 256, 256, 0, stream>>>(ei, dinv, cursor, csr_src, csr_norm);

    dim3 ggrid((NN + 255) / 256, 4);
    // conv1: t1 = x @ W1 -> A ; h1 = relu(agg(A) + b1) -> B
    gemm128f_k<<<ggrid, 256, 0, stream>>>(x, W1, A, NN);
    aggf_k<<<NN, 64, 0, stream>>>(A, rowptr, csr_src, csr_norm, dinv, b1, B, 1);
    // conv2: t2 = h1 @ W2 -> A ; h2 = relu(agg(A) + b2) -> B
    gemm128f_k<<<ggrid, 256, 0, stream>>>(B, W2, A, NN);
    aggf_k<<<NN, 64, 0, stream>>>(A, rowptr, csr_src, csr_norm, dinv, b2, B, 1);
    // pool + fc (latent out) + decoder(+W3 transform)
    pool_k<<<GG, 128, 0, stream>>>(B, batch, pooled);
    fc_k<<<GG, 64, 0, stream>>>(pooled, fcW, fcb, latentf, lat_out);
    dec_k<<<GG, 128, 0, stream>>>(latentf, decW, decb, W3, zz);
    // conv3 -> recon
    agg_out_k<<<NN, 64, 0, stream>>>(zz, batch, rowptr, csr_src, csr_norm, dinv,
                                     b3, recon_out);
}

// Round 3
// 518.849 us; speedup vs baseline: 1.2040x; 1.2040x over previous
//
#include <hip/hip_runtime.h>

// Problem constants
static constexpr int NN   = 50000;
static constexpr int EE   = 800000;
static constexpr int GG   = 256;
static constexpr int NBLK = (NN + 255) / 256;   // 196

// ---------- helpers ----------
__device__ __forceinline__ int lowerb(const int* __restrict__ b, int n, int v) {
    int lo = 0, hi = n;
    while (lo < hi) { int m = (lo + hi) >> 1; if (b[m] < v) lo = m + 1; else hi = m; }
    return lo;
}

// ---------- CSR build (by target node = col) ----------
__global__ void count_k(const int* __restrict__ ei, int* __restrict__ cnt)
{
    int e = blockIdx.x * 256 + threadIdx.x;
    if (e < EE) atomicAdd(&cnt[ei[EE + e]], 1);
}

// Phase B: per-block sums of cnt
__global__ __launch_bounds__(256) void bsum_k(const int* __restrict__ cnt, int* __restrict__ bsum)
{
    __shared__ int s[256];
    int b = blockIdx.x, t = threadIdx.x;
    int i = b * 256 + t;
    s[t] = (i < NN) ? cnt[i] : 0;
    __syncthreads();
    #pragma unroll
    for (int off = 128; off > 0; off >>= 1) {
        if (t < off) s[t] += s[t + off];
        __syncthreads();
    }
    if (t == 0) bsum[b] = s[0];
}

// Phase C: exclusive scan of block sums (single small block)
__global__ __launch_bounds__(256) void scanb_k(const int* __restrict__ bsum, int* __restrict__ boff)
{
    __shared__ int s[256];
    int t = threadIdx.x;
    int v = (t < NBLK) ? bsum[t] : 0;
    s[t] = v;
    __syncthreads();
    #pragma unroll
    for (int off = 1; off < 256; off <<= 1) {
        int add = (t >= off) ? s[t - off] : 0;
        __syncthreads();
        s[t] += add;
        __syncthreads();
    }
    boff[t] = s[t] - v;   // exclusive
}

// Phase D: intra-block exclusive scan + emit rowptr/cursor/dinv
__global__ __launch_bounds__(256) void emit_k(const int* __restrict__ cnt,
                                              const int* __restrict__ boff,
                                              int* __restrict__ rowptr,
                                              int* __restrict__ cursor,
                                              float* __restrict__ dinv)
{
    __shared__ int s[256];
    int b = blockIdx.x, t = threadIdx.x;
    int i = b * 256 + t;
    int v = (i < NN) ? cnt[i] : 0;
    s[t] = v;
    __syncthreads();
    #pragma unroll
    for (int off = 1; off < 256; off <<= 1) {
        int add = (t >= off) ? s[t - off] : 0;
        __syncthreads();
        s[t] += add;
        __syncthreads();
    }
    int run = boff[b] + s[t] - v;   // exclusive prefix
    if (i < NN) {
        rowptr[i] = run;
        cursor[i] = run;
        dinv[i]   = rsqrtf((float)(v + 1));   // deg includes self-loop
        if (i == NN - 1) rowptr[NN] = run + v;
    }
}

__global__ void fill_k(const int* __restrict__ ei, const float* __restrict__ dinv,
                       int* __restrict__ cursor, int* __restrict__ csr_src,
                       float* __restrict__ csr_norm)
{
    int e = blockIdx.x * 256 + threadIdx.x;
    if (e < EE) {
        int r = ei[e];          // source
        int c = ei[EE + e];     // target
        int p = atomicAdd(&cursor[c], 1);
        csr_src[p]  = r;
        csr_norm[p] = dinv[r] * dinv[c];
    }
}

// ---------- GEMM: out[r][c0..c0+32) = in[r][:] @ W[:, c0..c0+32)   (W row-major [128][128]) ----------
__global__ __launch_bounds__(256) void gemm128f_k(const float* __restrict__ in,
                                                  const float* __restrict__ W,
                                                  float* __restrict__ out,
                                                  int rows)
{
    int r = blockIdx.x * 256 + threadIdx.x;
    if (r >= rows) return;
    int c0 = blockIdx.y * 32;
    const float* rowp = in + (size_t)r * 128;

    float acc[32];
    #pragma unroll
    for (int j = 0; j < 32; j++) acc[j] = 0.f;

    for (int k0 = 0; k0 < 128; k0 += 8) {
        float4 ra = *(const float4*)(rowp + k0);
        float4 rb = *(const float4*)(rowp + k0 + 4);
        float rr[8] = {ra.x, ra.y, ra.z, ra.w, rb.x, rb.y, rb.z, rb.w};
        #pragma unroll
        for (int kk = 0; kk < 8; kk++) {
            const float* wr = W + (size_t)(k0 + kk) * 128 + c0;   // wave-uniform -> s_load
            #pragma unroll
            for (int j = 0; j < 32; j++) acc[j] = fmaf(rr[kk], wr[j], acc[j]);
        }
    }
    float* op = out + (size_t)r * 128 + c0;
    #pragma unroll
    for (int j = 0; j < 32; j += 4)
        *(float4*)(op + j) = make_float4(acc[j], acc[j+1], acc[j+2], acc[j+3]);
}

// ---------- aggregation: out[i] = relu?( sum_e norm*t[src] + dinv[i]^2 * t[i] + b ) ----------
__global__ __launch_bounds__(64) void aggf_k(const float* __restrict__ t,
                                             const int* __restrict__ rowptr,
                                             const int* __restrict__ csr_src,
                                             const float* __restrict__ csr_norm,
                                             const float* __restrict__ dinv,
                                             const float* __restrict__ bias,
                                             float* __restrict__ out,
                                             int relu)
{
    int i = blockIdx.x;
    int f = threadIdx.x;                      // float2 index, 64 covers 128 feats
    const float2* tp = (const float2*)t;
    float di = dinv[i];
    float sn = di * di;
    float2 v = tp[(size_t)i * 64 + f];
    float a0 = sn * v.x, a1 = sn * v.y;
    int e0 = rowptr[i], e1 = rowptr[i + 1];
    int e = e0;
    for (; e + 1 < e1; e += 2) {
        int s0 = csr_src[e],   s1 = csr_src[e + 1];
        float n0 = csr_norm[e], n1 = csr_norm[e + 1];
        float2 w0 = tp[(size_t)s0 * 64 + f];
        float2 w1 = tp[(size_t)s1 * 64 + f];
        a0 += n0 * w0.x; a1 += n0 * w0.y;
        a0 += n1 * w1.x; a1 += n1 * w1.y;
    }
    if (e < e1) {
        int s = csr_src[e];
        float nm = csr_norm[e];
        float2 w = tp[(size_t)s * 64 + f];
        a0 += nm * w.x; a1 += nm * w.y;
    }
    float2 b = ((const float2*)bias)[f];
    a0 += b.x; a1 += b.y;
    if (relu) { a0 = fmaxf(a0, 0.f); a1 = fmaxf(a1, 0.f); }
    ((float2*)out)[(size_t)i * 64 + f] = make_float2(a0, a1);
}

// conv3 aggregation: t row for node j is zz[batch[j]] (zz = z@W3, [G][128]); no relu
__global__ __launch_bounds__(64) void agg_out_k(const float* __restrict__ zz,
                                                const int* __restrict__ batch,
                                                const int* __restrict__ rowptr,
                                                const int* __restrict__ csr_src,
                                                const float* __restrict__ csr_norm,
                                                const float* __restrict__ dinv,
                                                const float* __restrict__ bias,
                                                float* __restrict__ out)
{
    int i = blockIdx.x;
    int f = threadIdx.x;
    const float2* zp = (const float2*)zz;     // only G*128 floats: L2-resident
    float di = dinv[i];
    float sn = di * di;
    float2 v = zp[(size_t)batch[i] * 64 + f];
    float a0 = sn * v.x, a1 = sn * v.y;
    int e0 = rowptr[i], e1 = rowptr[i + 1];
    for (int e = e0; e < e1; e++) {
        int s = csr_src[e];
        float nm = csr_norm[e];
        float2 w = zp[(size_t)batch[s] * 64 + f];
        a0 += nm * w.x; a1 += nm * w.y;
    }
    float2 b = ((const float2*)bias)[f];
    a0 += b.x; a1 += b.y;
    ((float2*)out)[(size_t)i * 64 + f] = make_float2(a0, a1);
}

// ---------- pooling: pooled[g][f] = sum over batch segment ----------
__global__ __launch_bounds__(128) void pool_k(const float* __restrict__ h2,
                                              const int* __restrict__ batch,
                                              float* __restrict__ pooled)
{
    int g = blockIdx.x;
    int f = threadIdx.x;                       // 0..127
    int bs = lowerb(batch, NN, g);
    int be = lowerb(batch, NN, g + 1);
    float a = 0.f;
    for (int i = bs; i < be; i++) a += h2[(size_t)i * 128 + f];
    pooled[(size_t)g * 128 + f] = a;
}

// ---------- fc: latent = relu(pooled @ fcW + fcb); writes latent to d_out too ----------
__global__ __launch_bounds__(64) void fc_k(const float* __restrict__ pooled,
                                           const float* __restrict__ fcW,    // [128][64]
                                           const float* __restrict__ fcb,
                                           float* __restrict__ latentf,
                                           float* __restrict__ lat_out)
{
    int g = blockIdx.x, l = threadIdx.x;       // 64 threads
    const float* p = pooled + (size_t)g * 128; // uniform scalar loads
    float a = fcb[l];
    #pragma unroll 8
    for (int k = 0; k < 128; k++) a = fmaf(p[k], fcW[(size_t)k * 64 + l], a);
    a = fmaxf(a, 0.f);
    latentf[(size_t)g * 64 + l] = a;
    lat_out[(size_t)g * 64 + l] = a;
}

// ---------- decoder + W3 transform: zz = relu(latent@decW + decb) @ W3 ----------
__global__ __launch_bounds__(128) void dec_k(const float* __restrict__ latentf,
                                             const float* __restrict__ decW,  // [64][128]
                                             const float* __restrict__ decb,
                                             const float* __restrict__ W3,    // [128][128]
                                             float* __restrict__ zz)
{
    __shared__ float zs[128];
    int g = blockIdx.x, c = threadIdx.x;       // 128 threads
    const float* lat = latentf + (size_t)g * 64;   // uniform
    {
        float a = decb[c];
        #pragma unroll 8
        for (int k = 0; k < 64; k++) a = fmaf(lat[k], decW[(size_t)k * 128 + c], a);
        zs[c] = fmaxf(a, 0.f);
    }
    __syncthreads();
    float o = 0.f;
    #pragma unroll 8
    for (int k = 0; k < 128; k++) o = fmaf(zs[k], W3[(size_t)k * 128 + c], o);
    zz[(size_t)g * 128 + c] = o;
}

extern "C" void kernel_launch(void* const* d_in, const int* in_sizes, int n_in,
                              void* d_out, int out_size, void* d_ws, size_t ws_size,
                              hipStream_t stream)
{
    const float* x     = (const float*)d_in[0];
    const int*   ei    = (const int*)d_in[1];
    const int*   batch = (const int*)d_in[2];
    const float* W1  = (const float*)d_in[3];
    const float* b1  = (const float*)d_in[4];
    const float* W2  = (const float*)d_in[5];
    const float* b2  = (const float*)d_in[6];
    const float* fcW = (const float*)d_in[7];
    const float* fcb = (const float*)d_in[8];
    const float* decW= (const float*)d_in[9];
    const float* decb= (const float*)d_in[10];
    const float* W3  = (const float*)d_in[11];
    const float* b3  = (const float*)d_in[12];

    char* ws = (char*)d_ws;
    size_t off = 0;
    auto alloc = [&](size_t bytes) -> char* {
        char* p = ws + off;
        off = (off + bytes + 255) & ~(size_t)255;
        return p;
    };
    float* dinv     = (float*)alloc((size_t)NN * 4);
    int*   cnt      = (int*)alloc((size_t)NN * 4);
    int*   rowptr   = (int*)alloc((size_t)(NN + 1) * 4);
    int*   cursor   = (int*)alloc((size_t)NN * 4);
    int*   bsum     = (int*)alloc((size_t)NBLK * 4);
    int*   boff     = (int*)alloc(256 * 4);
    int*   csr_src  = (int*)alloc((size_t)EE * 4);
    float* csr_norm = (float*)alloc((size_t)EE * 4);
    float* pooled   = (float*)alloc((size_t)GG * 128 * 4);
    float* latentf  = (float*)alloc((size_t)GG * 64 * 4);
    float* zz       = (float*)alloc((size_t)GG * 128 * 4);
    float* A        = (float*)alloc((size_t)NN * 128 * 4);   // transformed features t
    float* B        = (float*)alloc((size_t)NN * 128 * 4);   // hidden activations h

    float* recon_out = (float*)d_out;
    float* lat_out   = (float*)d_out + (size_t)NN * 128;

    hipMemsetAsync(cnt, 0, (size_t)NN * 4, stream);
    count_k<<<(EE + 255) / 256, 256, 0, stream>>>(ei, cnt);
    bsum_k<<<NBLK, 256, 0, stream>>>(cnt, bsum);
    scanb_k<<<1, 256, 0, stream>>>(bsum, boff);
    emit_k<<<NBLK, 256, 0, stream>>>(cnt, boff, rowptr, cursor, dinv);
    fill_k<<<(EE + 255) / 256, 256, 0, stream>>>(ei, dinv, cursor, csr_src, csr_norm);

    dim3 ggrid((NN + 255) / 256, 4);
    // conv1: t1 = x @ W1 -> A ; h1 = relu(agg(A) + b1) -> B
    gemm128f_k<<<ggrid, 256, 0, stream>>>(x, W1, A, NN);
    aggf_k<<<NN, 64, 0, stream>>>(A, rowptr, csr_src, csr_norm, dinv, b1, B, 1);
    // conv2: t2 = h1 @ W2 -> A ; h2 = relu(agg(A) + b2) -> B
    gemm128f_k<<<ggrid, 256, 0, stream>>>(B, W2, A, NN);
    aggf_k<<<NN, 64, 0, stream>>>(A, rowptr, csr_src, csr_norm, dinv, b2, B, 1);
    // pool + fc (latent out) + decoder(+W3 transform)
    pool_k<<<GG, 128, 0, stream>>>(B, batch, pooled);
    fc_k<<<GG, 64, 0, stream>>>(pooled, fcW, fcb, latentf, lat_out);
    dec_k<<<GG, 128, 0, stream>>>(latentf, decW, decb, W3, zz);
    // conv3 -> recon
    agg_out_k<<<NN, 64, 0, stream>>>(zz, batch, rowptr, csr_src, csr_norm, dinv,
                                     b3, recon_out);
}

// Round 4
// 467.361 us; speedup vs baseline: 1.3367x; 1.1102x over previous
//
#include <hip/hip_runtime.h>

// Problem constants
static constexpr int NN   = 50000;
static constexpr int EE   = 800000;
static constexpr int GG   = 256;
static constexpr int NBLK = (NN + 255) / 256;   // 196
static constexpr int PCH  = 16;                 // pooling chunks per graph

// ---------- helpers ----------
__device__ __forceinline__ int lowerb(const int* __restrict__ b, int n, int v) {
    int lo = 0, hi = n;
    while (lo < hi) { int m = (lo + hi) >> 1; if (b[m] < v) lo = m + 1; else hi = m; }
    return lo;
}

// ---------- CSR build (by target node = col) ----------
__global__ void count_k(const int* __restrict__ ei, int* __restrict__ cnt)
{
    int e = blockIdx.x * 256 + threadIdx.x;
    if (e < EE) atomicAdd(&cnt[ei[EE + e]], 1);
}

// Phase B: per-block sums of cnt
__global__ __launch_bounds__(256) void bsum_k(const int* __restrict__ cnt, int* __restrict__ bsum)
{
    __shared__ int s[256];
    int b = blockIdx.x, t = threadIdx.x;
    int i = b * 256 + t;
    s[t] = (i < NN) ? cnt[i] : 0;
    __syncthreads();
    #pragma unroll
    for (int off = 128; off > 0; off >>= 1) {
        if (t < off) s[t] += s[t + off];
        __syncthreads();
    }
    if (t == 0) bsum[b] = s[0];
}

// Phase C: exclusive scan of block sums (single small block)
__global__ __launch_bounds__(256) void scanb_k(const int* __restrict__ bsum, int* __restrict__ boff)
{
    __shared__ int s[256];
    int t = threadIdx.x;
    int v = (t < NBLK) ? bsum[t] : 0;
    s[t] = v;
    __syncthreads();
    #pragma unroll
    for (int off = 1; off < 256; off <<= 1) {
        int add = (t >= off) ? s[t - off] : 0;
        __syncthreads();
        s[t] += add;
        __syncthreads();
    }
    boff[t] = s[t] - v;   // exclusive
}

// Phase D: intra-block exclusive scan + emit rowptr/cursor/dinv
__global__ __launch_bounds__(256) void emit_k(const int* __restrict__ cnt,
                                              const int* __restrict__ boff,
                                              int* __restrict__ rowptr,
                                              int* __restrict__ cursor,
                                              float* __restrict__ dinv)
{
    __shared__ int s[256];
    int b = blockIdx.x, t = threadIdx.x;
    int i = b * 256 + t;
    int v = (i < NN) ? cnt[i] : 0;
    s[t] = v;
    __syncthreads();
    #pragma unroll
    for (int off = 1; off < 256; off <<= 1) {
        int add = (t >= off) ? s[t - off] : 0;
        __syncthreads();
        s[t] += add;
        __syncthreads();
    }
    int run = boff[b] + s[t] - v;   // exclusive prefix
    if (i < NN) {
        rowptr[i] = run;
        cursor[i] = run;
        dinv[i]   = rsqrtf((float)(v + 1));   // deg includes self-loop
        if (i == NN - 1) rowptr[NN] = run + v;
    }
}

__global__ void fill_k(const int* __restrict__ ei, const float* __restrict__ dinv,
                       int* __restrict__ cursor, int* __restrict__ csr_src,
                       float* __restrict__ csr_norm)
{
    int e = blockIdx.x * 256 + threadIdx.x;
    if (e < EE) {
        int r = ei[e];          // source
        int c = ei[EE + e];     // target
        int p = atomicAdd(&cursor[c], 1);
        csr_src[p]  = r;
        csr_norm[p] = dinv[r] * dinv[c];
    }
}

// ---------- GEMM: out[r][c0..c0+32) = in[r][:] @ W[:, c0..c0+32)   (W row-major [128][128]) ----------
__global__ __launch_bounds__(256) void gemm128f_k(const float* __restrict__ in,
                                                  const float* __restrict__ W,
                                                  float* __restrict__ out,
                                                  int rows)
{
    int r = blockIdx.x * 256 + threadIdx.x;
    if (r >= rows) return;
    int c0 = blockIdx.y * 32;
    const float* rowp = in + (size_t)r * 128;

    float acc[32];
    #pragma unroll
    for (int j = 0; j < 32; j++) acc[j] = 0.f;

    for (int k0 = 0; k0 < 128; k0 += 8) {
        float4 ra = *(const float4*)(rowp + k0);
        float4 rb = *(const float4*)(rowp + k0 + 4);
        float rr[8] = {ra.x, ra.y, ra.z, ra.w, rb.x, rb.y, rb.z, rb.w};
        #pragma unroll
        for (int kk = 0; kk < 8; kk++) {
            const float* wr = W + (size_t)(k0 + kk) * 128 + c0;   // wave-uniform -> s_load
            #pragma unroll
            for (int j = 0; j < 32; j++) acc[j] = fmaf(rr[kk], wr[j], acc[j]);
        }
    }
    float* op = out + (size_t)r * 128 + c0;
    #pragma unroll
    for (int j = 0; j < 32; j += 4)
        *(float4*)(op + j) = make_float4(acc[j], acc[j+1], acc[j+2], acc[j+3]);
}

// ---------- aggregation: out[i] = relu?( sum_e norm*t[src] + dinv[i]^2 * t[i] + b ) ----------
__global__ __launch_bounds__(64) void aggf_k(const float* __restrict__ t,
                                             const int* __restrict__ rowptr,
                                             const int* __restrict__ csr_src,
                                             const float* __restrict__ csr_norm,
                                             const float* __restrict__ dinv,
                                             const float* __restrict__ bias,
                                             float* __restrict__ out,
                                             int relu)
{
    int i = blockIdx.x;
    int f = threadIdx.x;                      // float2 index, 64 covers 128 feats
    const float2* tp = (const float2*)t;
    float di = dinv[i];
    float sn = di * di;
    float2 v = tp[(size_t)i * 64 + f];
    float a0 = sn * v.x, a1 = sn * v.y;
    int e0 = rowptr[i], e1 = rowptr[i + 1];
    int e = e0;
    for (; e + 1 < e1; e += 2) {
        int s0 = csr_src[e],   s1 = csr_src[e + 1];
        float n0 = csr_norm[e], n1 = csr_norm[e + 1];
        float2 w0 = tp[(size_t)s0 * 64 + f];
        float2 w1 = tp[(size_t)s1 * 64 + f];
        a0 += n0 * w0.x; a1 += n0 * w0.y;
        a0 += n1 * w1.x; a1 += n1 * w1.y;
    }
    if (e < e1) {
        int s = csr_src[e];
        float nm = csr_norm[e];
        float2 w = tp[(size_t)s * 64 + f];
        a0 += nm * w.x; a1 += nm * w.y;
    }
    float2 b = ((const float2*)bias)[f];
    a0 += b.x; a1 += b.y;
    if (relu) { a0 = fmaxf(a0, 0.f); a1 = fmaxf(a1, 0.f); }
    ((float2*)out)[(size_t)i * 64 + f] = make_float2(a0, a1);
}

// conv3 aggregation: t row for node j is zz[batch[j]] (zz = z@W3, [G][128]); no relu
__global__ __launch_bounds__(64) void agg_out_k(const float* __restrict__ zz,
                                                const int* __restrict__ batch,
                                                const int* __restrict__ rowptr,
                                                const int* __restrict__ csr_src,
                                                const float* __restrict__ csr_norm,
                                                const float* __restrict__ dinv,
                                                const float* __restrict__ bias,
                                                float* __restrict__ out)
{
    int i = blockIdx.x;
    int f = threadIdx.x;
    const float2* zp = (const float2*)zz;     // only G*128 floats: L2-resident
    float di = dinv[i];
    float sn = di * di;
    float2 v = zp[(size_t)batch[i] * 64 + f];
    float a0 = sn * v.x, a1 = sn * v.y;
    int e0 = rowptr[i], e1 = rowptr[i + 1];
    for (int e = e0; e < e1; e++) {
        int s = csr_src[e];
        float nm = csr_norm[e];
        float2 w = zp[(size_t)batch[s] * 64 + f];
        a0 += nm * w.x; a1 += nm * w.y;
    }
    float2 b = ((const float2*)bias)[f];
    a0 += b.x; a1 += b.y;
    ((float2*)out)[(size_t)i * 64 + f] = make_float2(a0, a1);
}

// ---------- pooling (parallel): pooled[g][f] += partial sums over chunk c of graph g ----------
__global__ __launch_bounds__(128) void pool2_k(const float* __restrict__ h2,
                                               const int* __restrict__ batch,
                                               float* __restrict__ pooled)
{
    int g = blockIdx.x;
    int c = blockIdx.y;
    int f = threadIdx.x;                       // 0..127
    int bs = lowerb(batch, NN, g);
    int be = lowerb(batch, NN, g + 1);
    int len = be - bs;
    int cs = bs + (int)(((long long)len * c) / PCH);
    int ce = bs + (int)(((long long)len * (c + 1)) / PCH);
    float a = 0.f;
    for (int i = cs; i < ce; i++) a += h2[(size_t)i * 128 + f];
    if (ce > cs) atomicAdd(&pooled[(size_t)g * 128 + f], a);
}

// ---------- fc: latent = relu(pooled @ fcW + fcb); writes latent to d_out too ----------
__global__ __launch_bounds__(64) void fc_k(const float* __restrict__ pooled,
                                           const float* __restrict__ fcW,    // [128][64]
                                           const float* __restrict__ fcb,
                                           float* __restrict__ latentf,
                                           float* __restrict__ lat_out)
{
    int g = blockIdx.x, l = threadIdx.x;       // 64 threads
    const float* p = pooled + (size_t)g * 128; // uniform scalar loads
    float a = fcb[l];
    #pragma unroll 8
    for (int k = 0; k < 128; k++) a = fmaf(p[k], fcW[(size_t)k * 64 + l], a);
    a = fmaxf(a, 0.f);
    latentf[(size_t)g * 64 + l] = a;
    lat_out[(size_t)g * 64 + l] = a;
}

// ---------- decoder + W3 transform: zz = relu(latent@decW + decb) @ W3 ----------
__global__ __launch_bounds__(128) void dec_k(const float* __restrict__ latentf,
                                             const float* __restrict__ decW,  // [64][128]
                                             const float* __restrict__ decb,
                                             const float* __restrict__ W3,    // [128][128]
                                             float* __restrict__ zz)
{
    __shared__ float zs[128];
    int g = blockIdx.x, c = threadIdx.x;       // 128 threads
    const float* lat = latentf + (size_t)g * 64;   // uniform
    {
        float a = decb[c];
        #pragma unroll 8
        for (int k = 0; k < 64; k++) a = fmaf(lat[k], decW[(size_t)k * 128 + c], a);
        zs[c] = fmaxf(a, 0.f);
    }
    __syncthreads();
    float o = 0.f;
    #pragma unroll 8
    for (int k = 0; k < 128; k++) o = fmaf(zs[k], W3[(size_t)k * 128 + c], o);
    zz[(size_t)g * 128 + c] = o;
}

extern "C" void kernel_launch(void* const* d_in, const int* in_sizes, int n_in,
                              void* d_out, int out_size, void* d_ws, size_t ws_size,
                              hipStream_t stream)
{
    const float* x     = (const float*)d_in[0];
    const int*   ei    = (const int*)d_in[1];
    const int*   batch = (const int*)d_in[2];
    const float* W1  = (const float*)d_in[3];
    const float* b1  = (const float*)d_in[4];
    const float* W2  = (const float*)d_in[5];
    const float* b2  = (const float*)d_in[6];
    const float* fcW = (const float*)d_in[7];
    const float* fcb = (const float*)d_in[8];
    const float* decW= (const float*)d_in[9];
    const float* decb= (const float*)d_in[10];
    const float* W3  = (const float*)d_in[11];
    const float* b3  = (const float*)d_in[12];

    char* ws = (char*)d_ws;
    size_t off = 0;
    auto alloc = [&](size_t bytes) -> char* {
        char* p = ws + off;
        off = (off + bytes + 255) & ~(size_t)255;
        return p;
    };
    float* dinv     = (float*)alloc((size_t)NN * 4);
    int*   cnt      = (int*)alloc((size_t)NN * 4);
    int*   rowptr   = (int*)alloc((size_t)(NN + 1) * 4);
    int*   cursor   = (int*)alloc((size_t)NN * 4);
    int*   bsum     = (int*)alloc((size_t)NBLK * 4);
    int*   boff     = (int*)alloc(256 * 4);
    int*   csr_src  = (int*)alloc((size_t)EE * 4);
    float* csr_norm = (float*)alloc((size_t)EE * 4);
    float* pooled   = (float*)alloc((size_t)GG * 128 * 4);
    float* latentf  = (float*)alloc((size_t)GG * 64 * 4);
    float* zz       = (float*)alloc((size_t)GG * 128 * 4);
    float* A        = (float*)alloc((size_t)NN * 128 * 4);   // transformed features t
    float* B        = (float*)alloc((size_t)NN * 128 * 4);   // hidden activations h

    float* recon_out = (float*)d_out;
    float* lat_out   = (float*)d_out + (size_t)NN * 128;

    hipMemsetAsync(cnt, 0, (size_t)NN * 4, stream);
    hipMemsetAsync(pooled, 0, (size_t)GG * 128 * 4, stream);
    count_k<<<(EE + 255) / 256, 256, 0, stream>>>(ei, cnt);
    bsum_k<<<NBLK, 256, 0, stream>>>(cnt, bsum);
    scanb_k<<<1, 256, 0, stream>>>(bsum, boff);
    emit_k<<<NBLK, 256, 0, stream>>>(cnt, boff, rowptr, cursor, dinv);
    fill_k<<<(EE + 255) / 256, 256, 0, stream>>>(ei, dinv, cursor, csr_src, csr_norm);

    dim3 ggrid((NN + 255) / 256, 4);
    // conv1: t1 = x @ W1 -> A ; h1 = relu(agg(A) + b1) -> B
    gemm128f_k<<<ggrid, 256, 0, stream>>>(x, W1, A, NN);
    aggf_k<<<NN, 64, 0, stream>>>(A, rowptr, csr_src, csr_norm, dinv, b1, B, 1);
    // conv2: t2 = h1 @ W2 -> A ; h2 = relu(agg(A) + b2) -> B
    gemm128f_k<<<ggrid, 256, 0, stream>>>(B, W2, A, NN);
    aggf_k<<<NN, 64, 0, stream>>>(A, rowptr, csr_src, csr_norm, dinv, b2, B, 1);
    // pool (parallel, atomic) + fc (latent out) + decoder(+W3 transform)
    pool2_k<<<dim3(GG, PCH), 128, 0, stream>>>(B, batch, pooled);
    fc_k<<<GG, 64, 0, stream>>>(pooled, fcW, fcb, latentf, lat_out);
    dec_k<<<GG, 128, 0, stream>>>(latentf, decW, decb, W3, zz);
    // conv3 -> recon
    agg_out_k<<<NN, 64, 0, stream>>>(zz, batch, rowptr, csr_src, csr_norm, dinv,
                                     b3, recon_out);
}

// Round 5
// 441.498 us; speedup vs baseline: 1.4150x; 1.0586x over previous
//
#include <hip/hip_runtime.h>

// Problem constants
static constexpr int NN   = 50000;
static constexpr int EE   = 800000;
static constexpr int GG   = 256;
static constexpr int NBLK = (NN + 255) / 256;   // 196
static constexpr int PCH  = 16;                 // pooling chunks per graph

// ---------- helpers ----------
__device__ __forceinline__ int lowerb(const int* __restrict__ b, int n, int v) {
    int lo = 0, hi = n;
    while (lo < hi) { int m = (lo + hi) >> 1; if (b[m] < v) lo = m + 1; else hi = m; }
    return lo;
}

// ---------- CSR build (by target node = col) ----------
__global__ void count_k(const int* __restrict__ ei, int* __restrict__ cnt)
{
    int e = blockIdx.x * 256 + threadIdx.x;
    if (e < EE) atomicAdd(&cnt[ei[EE + e]], 1);
}

// Phase B: per-block sums of cnt
__global__ __launch_bounds__(256) void bsum_k(const int* __restrict__ cnt, int* __restrict__ bsum)
{
    __shared__ int s[256];
    int b = blockIdx.x, t = threadIdx.x;
    int i = b * 256 + t;
    s[t] = (i < NN) ? cnt[i] : 0;
    __syncthreads();
    #pragma unroll
    for (int off = 128; off > 0; off >>= 1) {
        if (t < off) s[t] += s[t + off];
        __syncthreads();
    }
    if (t == 0) bsum[b] = s[0];
}

// Phase C: exclusive scan of block sums (single small block)
__global__ __launch_bounds__(256) void scanb_k(const int* __restrict__ bsum, int* __restrict__ boff)
{
    __shared__ int s[256];
    int t = threadIdx.x;
    int v = (t < NBLK) ? bsum[t] : 0;
    s[t] = v;
    __syncthreads();
    #pragma unroll
    for (int off = 1; off < 256; off <<= 1) {
        int add = (t >= off) ? s[t - off] : 0;
        __syncthreads();
        s[t] += add;
        __syncthreads();
    }
    boff[t] = s[t] - v;   // exclusive
}

// Phase D: intra-block exclusive scan + emit rowptr/cursor/dinv
__global__ __launch_bounds__(256) void emit_k(const int* __restrict__ cnt,
                                              const int* __restrict__ boff,
                                              int* __restrict__ rowptr,
                                              int* __restrict__ cursor,
                                              float* __restrict__ dinv)
{
    __shared__ int s[256];
    int b = blockIdx.x, t = threadIdx.x;
    int i = b * 256 + t;
    int v = (i < NN) ? cnt[i] : 0;
    s[t] = v;
    __syncthreads();
    #pragma unroll
    for (int off = 1; off < 256; off <<= 1) {
        int add = (t >= off) ? s[t - off] : 0;
        __syncthreads();
        s[t] += add;
        __syncthreads();
    }
    int run = boff[b] + s[t] - v;   // exclusive prefix
    if (i < NN) {
        rowptr[i] = run;
        cursor[i] = run;
        dinv[i]   = rsqrtf((float)(v + 1));   // deg includes self-loop
        if (i == NN - 1) rowptr[NN] = run + v;
    }
}

// fill packed edge records {src, norm} — ONE scattered 8B write per edge
__global__ void fill_k(const int* __restrict__ ei, const float* __restrict__ dinv,
                       int* __restrict__ cursor, int2* __restrict__ ebuf)
{
    int e = blockIdx.x * 256 + threadIdx.x;
    if (e < EE) {
        int r = ei[e];          // source
        int c = ei[EE + e];     // target
        int p = atomicAdd(&cursor[c], 1);
        ebuf[p] = make_int2(r, __float_as_int(dinv[r] * dinv[c]));
    }
}

// edge-parallel: ebuf2[e] = {batch[src], norm} (coalesced both ways)
__global__ void pb_k(const int2* __restrict__ ebuf, const int* __restrict__ batch,
                     int2* __restrict__ ebuf2)
{
    int e = blockIdx.x * 256 + threadIdx.x;
    if (e < EE) {
        int2 r = ebuf[e];
        ebuf2[e] = make_int2(batch[r.x], r.y);
    }
}

// ---------- GEMM: out[r][c0..c0+32) = in[r][:] @ W[:, c0..c0+32)   (W row-major [128][128]) ----------
__global__ __launch_bounds__(256) void gemm128f_k(const float* __restrict__ in,
                                                  const float* __restrict__ W,
                                                  float* __restrict__ out,
                                                  int rows)
{
    int r = blockIdx.x * 256 + threadIdx.x;
    if (r >= rows) return;
    int c0 = blockIdx.y * 32;
    const float* rowp = in + (size_t)r * 128;

    float acc[32];
    #pragma unroll
    for (int j = 0; j < 32; j++) acc[j] = 0.f;

    for (int k0 = 0; k0 < 128; k0 += 8) {
        float4 ra = *(const float4*)(rowp + k0);
        float4 rb = *(const float4*)(rowp + k0 + 4);
        float rr[8] = {ra.x, ra.y, ra.z, ra.w, rb.x, rb.y, rb.z, rb.w};
        #pragma unroll
        for (int kk = 0; kk < 8; kk++) {
            const float* wr = W + (size_t)(k0 + kk) * 128 + c0;   // wave-uniform -> s_load
            #pragma unroll
            for (int j = 0; j < 32; j++) acc[j] = fmaf(rr[kk], wr[j], acc[j]);
        }
    }
    float* op = out + (size_t)r * 128 + c0;
    #pragma unroll
    for (int j = 0; j < 32; j += 4)
        *(float4*)(op + j) = make_float4(acc[j], acc[j+1], acc[j+2], acc[j+3]);
}

// ---------- aggregation: out[i] = relu?( sum_e norm*t[src] + dinv[i]^2 * t[i] + b ) ----------
// block = node, 64 threads = float2 feature pairs; edge loop unrolled x4 for MLP
__global__ __launch_bounds__(64) void aggf_k(const float* __restrict__ t,
                                             const int* __restrict__ rowptr,
                                             const int2* __restrict__ ebuf,
                                             const float* __restrict__ dinv,
                                             const float* __restrict__ bias,
                                             float* __restrict__ out,
                                             int relu)
{
    int i = blockIdx.x;
    int f = threadIdx.x;
    const float2* tp = (const float2*)t;
    float di = dinv[i];
    float sn = di * di;
    float2 v = tp[(size_t)i * 64 + f];
    float a0 = sn * v.x, a1 = sn * v.y;
    int e0 = rowptr[i], e1 = rowptr[i + 1];
    int e = e0;
    for (; e + 3 < e1; e += 4) {
        int2 r0 = ebuf[e],     r1 = ebuf[e + 1];
        int2 r2 = ebuf[e + 2], r3 = ebuf[e + 3];
        float2 w0 = tp[(size_t)r0.x * 64 + f];
        float2 w1 = tp[(size_t)r1.x * 64 + f];
        float2 w2 = tp[(size_t)r2.x * 64 + f];
        float2 w3 = tp[(size_t)r3.x * 64 + f];
        float n0 = __int_as_float(r0.y), n1 = __int_as_float(r1.y);
        float n2 = __int_as_float(r2.y), n3 = __int_as_float(r3.y);
        a0 += n0 * w0.x; a1 += n0 * w0.y;
        a0 += n1 * w1.x; a1 += n1 * w1.y;
        a0 += n2 * w2.x; a1 += n2 * w2.y;
        a0 += n3 * w3.x; a1 += n3 * w3.y;
    }
    for (; e < e1; e++) {
        int2 r = ebuf[e];
        float nm = __int_as_float(r.y);
        float2 w = tp[(size_t)r.x * 64 + f];
        a0 += nm * w.x; a1 += nm * w.y;
    }
    float2 b = ((const float2*)bias)[f];
    a0 += b.x; a1 += b.y;
    if (relu) { a0 = fmaxf(a0, 0.f); a1 = fmaxf(a1, 0.f); }
    ((float2*)out)[(size_t)i * 64 + f] = make_float2(a0, a1);
}

// conv3 aggregation: row for edge src is zz[bg] where ebuf2 = {bg, norm}; zz L2-resident
__global__ __launch_bounds__(64) void agg_out_k(const float* __restrict__ zz,
                                                const int* __restrict__ batch,
                                                const int* __restrict__ rowptr,
                                                const int2* __restrict__ ebuf2,
                                                const float* __restrict__ dinv,
                                                const float* __restrict__ bias,
                                                float* __restrict__ out)
{
    int i = blockIdx.x;
    int f = threadIdx.x;
    const float2* zp = (const float2*)zz;
    float di = dinv[i];
    float sn = di * di;
    float2 v = zp[(size_t)batch[i] * 64 + f];
    float a0 = sn * v.x, a1 = sn * v.y;
    int e0 = rowptr[i], e1 = rowptr[i + 1];
    int e = e0;
    for (; e + 3 < e1; e += 4) {
        int2 r0 = ebuf2[e],     r1 = ebuf2[e + 1];
        int2 r2 = ebuf2[e + 2], r3 = ebuf2[e + 3];
        float2 w0 = zp[(size_t)r0.x * 64 + f];
        float2 w1 = zp[(size_t)r1.x * 64 + f];
        float2 w2 = zp[(size_t)r2.x * 64 + f];
        float2 w3 = zp[(size_t)r3.x * 64 + f];
        float n0 = __int_as_float(r0.y), n1 = __int_as_float(r1.y);
        float n2 = __int_as_float(r2.y), n3 = __int_as_float(r3.y);
        a0 += n0 * w0.x; a1 += n0 * w0.y;
        a0 += n1 * w1.x; a1 += n1 * w1.y;
        a0 += n2 * w2.x; a1 += n2 * w2.y;
        a0 += n3 * w3.x; a1 += n3 * w3.y;
    }
    for (; e < e1; e++) {
        int2 r = ebuf2[e];
        float nm = __int_as_float(r.y);
        float2 w = zp[(size_t)r.x * 64 + f];
        a0 += nm * w.x; a1 += nm * w.y;
    }
    float2 b = ((const float2*)bias)[f];
    a0 += b.x; a1 += b.y;
    ((float2*)out)[(size_t)i * 64 + f] = make_float2(a0, a1);
}

// ---------- pooling (parallel): pooled[g][f] += partial sums over chunk c of graph g ----------
__global__ __launch_bounds__(128) void pool2_k(const float* __restrict__ h2,
                                               const int* __restrict__ batch,
                                               float* __restrict__ pooled)
{
    int g = blockIdx.x;
    int c = blockIdx.y;
    int f = threadIdx.x;
    int bs = lowerb(batch, NN, g);
    int be = lowerb(batch, NN, g + 1);
    int len = be - bs;
    int cs = bs + (int)(((long long)len * c) / PCH);
    int ce = bs + (int)(((long long)len * (c + 1)) / PCH);
    float a = 0.f;
    for (int i = cs; i < ce; i++) a += h2[(size_t)i * 128 + f];
    if (ce > cs) atomicAdd(&pooled[(size_t)g * 128 + f], a);
}

// ---------- fc: latent = relu(pooled @ fcW + fcb); writes latent to d_out too ----------
__global__ __launch_bounds__(64) void fc_k(const float* __restrict__ pooled,
                                           const float* __restrict__ fcW,    // [128][64]
                                           const float* __restrict__ fcb,
                                           float* __restrict__ latentf,
                                           float* __restrict__ lat_out)
{
    int g = blockIdx.x, l = threadIdx.x;
    const float* p = pooled + (size_t)g * 128;
    float a = fcb[l];
    #pragma unroll 8
    for (int k = 0; k < 128; k++) a = fmaf(p[k], fcW[(size_t)k * 64 + l], a);
    a = fmaxf(a, 0.f);
    latentf[(size_t)g * 64 + l] = a;
    lat_out[(size_t)g * 64 + l] = a;
}

// ---------- decoder + W3 transform: zz = relu(latent@decW + decb) @ W3 ----------
__global__ __launch_bounds__(128) void dec_k(const float* __restrict__ latentf,
                                             const float* __restrict__ decW,  // [64][128]
                                             const float* __restrict__ decb,
                                             const float* __restrict__ W3,    // [128][128]
                                             float* __restrict__ zz)
{
    __shared__ float zs[128];
    int g = blockIdx.x, c = threadIdx.x;
    const float* lat = latentf + (size_t)g * 64;
    {
        float a = decb[c];
        #pragma unroll 8
        for (int k = 0; k < 64; k++) a = fmaf(lat[k], decW[(size_t)k * 128 + c], a);
        zs[c] = fmaxf(a, 0.f);
    }
    __syncthreads();
    float o = 0.f;
    #pragma unroll 8
    for (int k = 0; k < 128; k++) o = fmaf(zs[k], W3[(size_t)k * 128 + c], o);
    zz[(size_t)g * 128 + c] = o;
}

extern "C" void kernel_launch(void* const* d_in, const int* in_sizes, int n_in,
                              void* d_out, int out_size, void* d_ws, size_t ws_size,
                              hipStream_t stream)
{
    const float* x     = (const float*)d_in[0];
    const int*   ei    = (const int*)d_in[1];
    const int*   batch = (const int*)d_in[2];
    const float* W1  = (const float*)d_in[3];
    const float* b1  = (const float*)d_in[4];
    const float* W2  = (const float*)d_in[5];
    const float* b2  = (const float*)d_in[6];
    const float* fcW = (const float*)d_in[7];
    const float* fcb = (const float*)d_in[8];
    const float* decW= (const float*)d_in[9];
    const float* decb= (const float*)d_in[10];
    const float* W3  = (const float*)d_in[11];
    const float* b3  = (const float*)d_in[12];

    char* ws = (char*)d_ws;
    size_t off = 0;
    auto alloc = [&](size_t bytes) -> char* {
        char* p = ws + off;
        off = (off + bytes + 255) & ~(size_t)255;
        return p;
    };
    float* dinv     = (float*)alloc((size_t)NN * 4);
    int*   cnt      = (int*)alloc((size_t)NN * 4);
    int*   rowptr   = (int*)alloc((size_t)(NN + 1) * 4);
    int*   cursor   = (int*)alloc((size_t)NN * 4);
    int*   bsum     = (int*)alloc((size_t)NBLK * 4);
    int*   boff     = (int*)alloc(256 * 4);
    int2*  ebuf     = (int2*)alloc((size_t)EE * 8);          // packed {src, norm}
    float* pooled   = (float*)alloc((size_t)GG * 128 * 4);
    float* latentf  = (float*)alloc((size_t)GG * 64 * 4);
    float* zz       = (float*)alloc((size_t)GG * 128 * 4);
    float* A        = (float*)alloc((size_t)NN * 128 * 4);   // transformed features t
    float* B        = (float*)alloc((size_t)NN * 128 * 4);   // hidden activations h
    // ebuf2 aliases A: built only AFTER the 2nd aggf has consumed A
    int2*  ebuf2    = (int2*)A;

    float* recon_out = (float*)d_out;
    float* lat_out   = (float*)d_out + (size_t)NN * 128;

    hipMemsetAsync(cnt, 0, (size_t)NN * 4, stream);
    hipMemsetAsync(pooled, 0, (size_t)GG * 128 * 4, stream);
    count_k<<<(EE + 255) / 256, 256, 0, stream>>>(ei, cnt);
    bsum_k<<<NBLK, 256, 0, stream>>>(cnt, bsum);
    scanb_k<<<1, 256, 0, stream>>>(bsum, boff);
    emit_k<<<NBLK, 256, 0, stream>>>(cnt, boff, rowptr, cursor, dinv);
    fill_k<<<(EE + 255) / 256, 256, 0, stream>>>(ei, dinv, cursor, ebuf);

    dim3 ggrid((NN + 255) / 256, 4);
    // conv1: t1 = x @ W1 -> A ; h1 = relu(agg(A) + b1) -> B
    gemm128f_k<<<ggrid, 256, 0, stream>>>(x, W1, A, NN);
    aggf_k<<<NN, 64, 0, stream>>>(A, rowptr, ebuf, dinv, b1, B, 1);
    // conv2: t2 = h1 @ W2 -> A ; h2 = relu(agg(A) + b2) -> B
    gemm128f_k<<<ggrid, 256, 0, stream>>>(B, W2, A, NN);
    aggf_k<<<NN, 64, 0, stream>>>(A, rowptr, ebuf, dinv, b2, B, 1);
    // A is now free -> build ebuf2 in its space
    pb_k<<<(EE + 255) / 256, 256, 0, stream>>>(ebuf, batch, ebuf2);
    // pool + fc (latent out) + decoder(+W3 transform)
    pool2_k<<<dim3(GG, PCH), 128, 0, stream>>>(B, batch, pooled);
    fc_k<<<GG, 64, 0, stream>>>(pooled, fcW, fcb, latentf, lat_out);
    dec_k<<<GG, 128, 0, stream>>>(latentf, decW, decb, W3, zz);
    // conv3 -> recon
    agg_out_k<<<NN, 64, 0, stream>>>(zz, batch, rowptr, ebuf2, dinv,
                                     b3, recon_out);
}